// Round 1
// baseline (7629.329 us; speedup 1.0000x reference)
//
#include <hip/hip_runtime.h>
#include <hip/hip_bf16.h>

#define NN 16000
#define CC 128
#define EE 256000
#define AA 10

__device__ __forceinline__ float silu_f(float x) {
    return x / (1.0f + __expf(-x));
}

// ---------------- K1: h0/h1 pre-linears -> h (N,128) float4 [h0, h1x, h1y, h1z]
__global__ __launch_bounds__(256) void pre_kernel(const float* __restrict__ nf,
                                                  const float* __restrict__ Wpre0,
                                                  const float* __restrict__ Wpre1,
                                                  float4* __restrict__ h4) {
    __shared__ float4 lx[2][CC];
    const int c = threadIdx.x & 127;
    const int sub = threadIdx.x >> 7;
    const float inv_c = 0.08838834764831843f;
    const int base = blockIdx.x * 32;
    for (int it = 0; it < 16; ++it) {
        const int n = base + it * 2 + sub;
        const float* row = nf + (size_t)n * 512;
        lx[sub][c] = make_float4(row[c], row[128 + 3 * c], row[128 + 3 * c + 1], row[128 + 3 * c + 2]);
        __syncthreads();
        float4 acc = make_float4(0.f, 0.f, 0.f, 0.f);
        #pragma unroll 8
        for (int u = 0; u < 128; ++u) {
            const float w0 = Wpre0[u * 128 + c];
            const float w1 = Wpre1[u * 128 + c];
            const float4 xv = lx[sub][u];
            acc.x += w0 * xv.x;
            acc.y += w1 * xv.y;
            acc.z += w1 * xv.z;
            acc.w += w1 * xv.w;
        }
        acc.x *= inv_c; acc.y *= inv_c; acc.z *= inv_c; acc.w *= inv_c;
        h4[(size_t)n * 128 + c] = acc;
        __syncthreads();
    }
}

// ---------------- K2: radial MLP -> hm (64, E) transposed
__global__ __launch_bounds__(256) void mlp_kernel(const float* __restrict__ rb,
                                                  const float* __restrict__ Wm1,
                                                  const float* __restrict__ Wm2,
                                                  float* __restrict__ hm) {
    __shared__ float4 sW1[8][16];
    __shared__ float4 sW2[64][16];
    const int tid = threadIdx.x;
    for (int i = tid; i < 8 * 16; i += 256) ((float4*)sW1)[i] = ((const float4*)Wm1)[i];
    for (int i = tid; i < 64 * 16; i += 256) ((float4*)sW2)[i] = ((const float4*)Wm2)[i];
    __syncthreads();
    const int e = blockIdx.x * 256 + tid;
    const float4* rb4 = (const float4*)(rb + (size_t)e * 8);
    const float4 r0 = rb4[0], r1 = rb4[1];
    float r[8] = {r0.x, r0.y, r0.z, r0.w, r1.x, r1.y, r1.z, r1.w};
    float h1[64];
    #pragma unroll
    for (int o4 = 0; o4 < 16; ++o4) {
        float4 a = make_float4(0.f, 0.f, 0.f, 0.f);
        #pragma unroll
        for (int k = 0; k < 8; ++k) {
            const float4 wv = sW1[k][o4];
            a.x += r[k] * wv.x; a.y += r[k] * wv.y; a.z += r[k] * wv.z; a.w += r[k] * wv.w;
        }
        h1[o4 * 4 + 0] = silu_f(a.x);
        h1[o4 * 4 + 1] = silu_f(a.y);
        h1[o4 * 4 + 2] = silu_f(a.z);
        h1[o4 * 4 + 3] = silu_f(a.w);
    }
    #pragma unroll
    for (int o4 = 0; o4 < 16; ++o4) {
        float4 a = make_float4(0.f, 0.f, 0.f, 0.f);
        #pragma unroll 8
        for (int k = 0; k < 64; ++k) {
            const float4 wv = sW2[k][o4];
            a.x += h1[k] * wv.x; a.y += h1[k] * wv.y; a.z += h1[k] * wv.z; a.w += h1[k] * wv.w;
        }
        hm[(size_t)(o4 * 4 + 0) * EE + e] = silu_f(a.x);
        hm[(size_t)(o4 * 4 + 1) * EE + e] = silu_f(a.y);
        hm[(size_t)(o4 * 4 + 2) * EE + e] = silu_f(a.z);
        hm[(size_t)(o4 * 4 + 3) * EE + e] = silu_f(a.w);
    }
}

// ---------------- K3: w-GEMM (E x 512, K=64) fused with messages + atomic scatter
// grid: (E/128, 4 groups). Acat layout: (N, 4, 256): d=0 -> A0(256), d=1..3 -> A1[:, :, d-1]
__global__ __launch_bounds__(256) void wmsg_kernel(const float* __restrict__ hm,
                                                   const float* __restrict__ Wm3,
                                                   const int* __restrict__ ei,
                                                   const float4* __restrict__ sph4,
                                                   const float4* __restrict__ h4,
                                                   float* __restrict__ Acat) {
    __shared__ float sA[64][128];
    __shared__ float sB[64][128];
    __shared__ int ls[128];
    __shared__ int lr[128];
    __shared__ float4 lY[128];
    const int tid = threadIdx.x;
    const int g = blockIdx.y;
    const int ebase = blockIdx.x * 128;

    for (int i = tid; i < 64 * 128; i += 256) {
        const int k = i >> 7, e = i & 127;
        sA[k][e] = hm[(size_t)k * EE + ebase + e];
    }
    for (int i = tid; i < 64 * 128; i += 256) {
        const int k = i >> 7, c = i & 127;
        sB[k][c] = Wm3[k * 512 + g * 128 + c];
    }
    if (tid < 128) {
        ls[tid] = ei[ebase + tid];
        lr[tid] = ei[EE + ebase + tid];
        lY[tid] = sph4[ebase + tid];
    }
    __syncthreads();

    const int tx = tid & 15, ty = tid >> 4;
    const int c0 = tx * 8, e0 = ty * 8;
    float acc[8][8];
    #pragma unroll
    for (int i = 0; i < 8; ++i)
        #pragma unroll
        for (int j = 0; j < 8; ++j) acc[i][j] = 0.f;

    #pragma unroll 4
    for (int u = 0; u < 64; ++u) {
        const float4 a0 = *(const float4*)&sA[u][e0];
        const float4 a1 = *(const float4*)&sA[u][e0 + 4];
        const float4 b0 = *(const float4*)&sB[u][c0];
        const float4 b1 = *(const float4*)&sB[u][c0 + 4];
        const float av[8] = {a0.x, a0.y, a0.z, a0.w, a1.x, a1.y, a1.z, a1.w};
        const float bv[8] = {b0.x, b0.y, b0.z, b0.w, b1.x, b1.y, b1.z, b1.w};
        #pragma unroll
        for (int i = 0; i < 8; ++i)
            #pragma unroll
            for (int j = 0; j < 8; ++j) acc[i][j] += av[i] * bv[j];
    }

    // epilogue: messages + atomic scatter
    #pragma unroll
    for (int i = 0; i < 8; ++i) {
        const int el = e0 + i;
        const int s = ls[el];
        const int r = lr[el];
        const float4 Y = lY[el];
        float* arow = Acat + (size_t)r * 1024;
        const float4* hrow = h4 + (size_t)s * 128;
        #pragma unroll
        for (int j = 0; j < 8; ++j) {
            const int c = c0 + j;
            const float w = acc[i][j];
            const float4 hv = hrow[c];
            if (g == 0) {
                atomicAdd(arow + c, w * hv.x * Y.x);
            } else if (g == 1) {
                const float dot = hv.y * Y.y + hv.z * Y.z + hv.w * Y.w;
                atomicAdd(arow + 128 + c, w * dot * 0.5773502691896258f);
            } else if (g == 2) {
                const float m = w * hv.x;
                atomicAdd(arow + 256 + c, m * Y.y);
                atomicAdd(arow + 512 + c, m * Y.z);
                atomicAdd(arow + 768 + c, m * Y.w);
            } else {
                const float m = w * Y.x;
                atomicAdd(arow + 256 + 128 + c, m * hv.y);
                atomicAdd(arow + 512 + 128 + c, m * hv.z);
                atomicAdd(arow + 768 + 128 + c, m * hv.w);
            }
        }
    }
}

// ---------------- K4: o = Acat @ Wpost, o layout (N, 4, 128)
__global__ __launch_bounds__(256) void posto_kernel(const float* __restrict__ Acat,
                                                    const float* __restrict__ Wpost0,
                                                    const float* __restrict__ Wpost1,
                                                    float* __restrict__ o) {
    __shared__ float sA[4][256][16];
    const int tid = threadIdx.x;
    const int nb = blockIdx.x * 16;
    {
        const int n = tid & 15, idx = tid >> 4;
        const float4* row4 = (const float4*)(Acat + (size_t)(nb + n) * 1024);
        #pragma unroll
        for (int rr = 0; rr < 16; ++rr) {
            const int f4 = idx + rr * 16;
            const float4 v = row4[f4];
            const int flat = f4 * 4;
            const int d = flat >> 8;
            const int u = flat & 255;
            sA[d][u + 0][n] = v.x;
            sA[d][u + 1][n] = v.y;
            sA[d][u + 2][n] = v.z;
            sA[d][u + 3][n] = v.w;
        }
    }
    __syncthreads();
    const int c = tid & 127, half = tid >> 7, dlo = half * 2;
    const float* W0 = (half == 0) ? Wpost0 : Wpost1;
    float acc0[16], acc1[16];
    #pragma unroll
    for (int n = 0; n < 16; ++n) { acc0[n] = 0.f; acc1[n] = 0.f; }
    #pragma unroll 2
    for (int u = 0; u < 256; ++u) {
        const float w0 = W0[u * 128 + c];
        const float w1 = Wpost1[u * 128 + c];
        #pragma unroll
        for (int n = 0; n < 16; ++n) {
            acc0[n] += sA[dlo][u][n] * w0;
            acc1[n] += sA[dlo + 1][u][n] * w1;
        }
    }
    const float inv_2c = 0.0625f;
    #pragma unroll
    for (int n = 0; n < 16; ++n) {
        o[((size_t)(nb + n) * 4 + dlo) * 128 + c] = acc0[n] * inv_2c;
        o[((size_t)(nb + n) * 4 + dlo + 1) * 128 + c] = acc1[n] * inv_2c;
    }
}

// ---------------- K5: attribute contraction + final output (N, 128, 4)
// grid: (N/64, 4)
__global__ __launch_bounds__(256) void attr_kernel(const float* __restrict__ o,
                                                   const float* __restrict__ attr,
                                                   const float* __restrict__ Wa0,
                                                   const float* __restrict__ Wa1,
                                                   float* __restrict__ out) {
    __shared__ float so[128][64];
    __shared__ float sB[64][128];
    __shared__ float sat[64][10];
    const int tid = threadIdx.x;
    const int d = blockIdx.y;
    const int nb = blockIdx.x * 64;
    const float* Wa = (d == 0) ? Wa0 : Wa1;
    {
        const int n = tid >> 2, q = tid & 3;
        const float4* row4 = (const float4*)(o + ((size_t)(nb + n) * 4 + d) * 128);
        #pragma unroll
        for (int rr = 0; rr < 8; ++rr) {
            const int f4 = q * 8 + rr;
            const float4 v = row4[f4];
            const int u = f4 * 4;
            so[u + 0][n] = v.x;
            so[u + 1][n] = v.y;
            so[u + 2][n] = v.z;
            so[u + 3][n] = v.w;
        }
    }
    if (tid < 64) {
        #pragma unroll
        for (int v = 0; v < 10; ++v) sat[tid][v] = attr[(size_t)(nb + tid) * 10 + v];
    }
    __syncthreads();

    const int tx = tid & 31, ty = tid >> 5;
    const int w0 = tx * 4, n0 = ty * 8;
    float acc[8][4];
    #pragma unroll
    for (int i = 0; i < 8; ++i)
        #pragma unroll
        for (int j = 0; j < 4; ++j) acc[i][j] = 0.f;

    for (int v = 0; v < 10; ++v) {
        float satv[8];
        #pragma unroll
        for (int i = 0; i < 8; ++i) satv[i] = sat[n0 + i][v];
        for (int uc = 0; uc < 2; ++uc) {
            __syncthreads();
            for (int i = tid; i < 64 * 128; i += 256) {
                const int uu = i >> 7, w = i & 127;
                sB[uu][w] = Wa[(size_t)(uc * 64 + uu) * 1280 + v * 128 + w];
            }
            __syncthreads();
            #pragma unroll 4
            for (int uu = 0; uu < 64; ++uu) {
                const int u = uc * 64 + uu;
                const float4 a0 = *(const float4*)&so[u][n0];
                const float4 a1 = *(const float4*)&so[u][n0 + 4];
                const float4 b = *(const float4*)&sB[uu][w0];
                const float av[8] = {a0.x * satv[0], a0.y * satv[1], a0.z * satv[2], a0.w * satv[3],
                                     a1.x * satv[4], a1.y * satv[5], a1.z * satv[6], a1.w * satv[7]};
                #pragma unroll
                for (int i = 0; i < 8; ++i) {
                    acc[i][0] += av[i] * b.x;
                    acc[i][1] += av[i] * b.y;
                    acc[i][2] += av[i] * b.z;
                    acc[i][3] += av[i] * b.w;
                }
            }
        }
    }
    const float inv_ca = 0.027950849718747373f;
    #pragma unroll
    for (int i = 0; i < 8; ++i)
        #pragma unroll
        for (int j = 0; j < 4; ++j)
            out[((size_t)(nb + n0 + i) * 128 + (w0 + j)) * 4 + d] = acc[i][j] * inv_ca;
}

extern "C" void kernel_launch(void* const* d_in, const int* in_sizes, int n_in,
                              void* d_out, int out_size, void* d_ws, size_t ws_size,
                              hipStream_t stream) {
    const float* nf    = (const float*)d_in[0];
    const float* attr  = (const float*)d_in[1];
    const float* sph   = (const float*)d_in[2];
    const float* rb    = (const float*)d_in[3];
    const int*   ei    = (const int*)d_in[4];
    const float* Wpre0 = (const float*)d_in[5];
    const float* Wpre1 = (const float*)d_in[6];
    const float* Wm1   = (const float*)d_in[7];
    const float* Wm2   = (const float*)d_in[8];
    const float* Wm3   = (const float*)d_in[9];
    const float* Wpost0= (const float*)d_in[10];
    const float* Wpost1= (const float*)d_in[11];
    const float* Wa0   = (const float*)d_in[12];
    const float* Wa1   = (const float*)d_in[13];
    float* out = (float*)d_out;

    float* ws = (float*)d_ws;
    // layout: h (N*128 float4 = 8,192,000 f) | hm (64*E = 16,384,000 f) | Acat (N*1024 = 16,384,000 f)
    float4* h4  = (float4*)ws;
    float* hm   = ws + (size_t)8192000;
    float* Acat = hm + (size_t)16384000;
    float* o    = ws;  // alias h region (h dead after wmsg_kernel)

    hipMemsetAsync(Acat, 0, (size_t)NN * 1024 * sizeof(float), stream);

    pre_kernel<<<500, 256, 0, stream>>>(nf, Wpre0, Wpre1, h4);
    mlp_kernel<<<EE / 256, 256, 0, stream>>>(rb, Wm1, Wm2, hm);
    wmsg_kernel<<<dim3(EE / 128, 4), 256, 0, stream>>>(hm, Wm3, ei, (const float4*)sph, h4, Acat);
    posto_kernel<<<NN / 16, 256, 0, stream>>>(Acat, Wpost0, Wpost1, o);
    attr_kernel<<<dim3(NN / 64, 4), 256, 0, stream>>>(o, attr, Wa0, Wa1, out);
}

// Round 2
// 3446.685 us; speedup vs baseline: 2.2135x; 2.2135x over previous
//
#include <hip/hip_runtime.h>
#include <hip/hip_bf16.h>

#define NN 16000
#define CC 128
#define EE 256000
#define AA 10

__device__ __forceinline__ float silu_f(float x) {
    return x / (1.0f + __expf(-x));
}

// ---------------- K1: h0/h1 pre-linears -> h (N,128) float4 [h0, h1x, h1y, h1z]
__global__ __launch_bounds__(256) void pre_kernel(const float* __restrict__ nf,
                                                  const float* __restrict__ Wpre0,
                                                  const float* __restrict__ Wpre1,
                                                  float4* __restrict__ h4) {
    __shared__ float4 lx[2][CC];
    const int c = threadIdx.x & 127;
    const int sub = threadIdx.x >> 7;
    const float inv_c = 0.08838834764831843f;
    const int base = blockIdx.x * 32;
    for (int it = 0; it < 16; ++it) {
        const int n = base + it * 2 + sub;
        const float* row = nf + (size_t)n * 512;
        lx[sub][c] = make_float4(row[c], row[128 + 3 * c], row[128 + 3 * c + 1], row[128 + 3 * c + 2]);
        __syncthreads();
        float4 acc = make_float4(0.f, 0.f, 0.f, 0.f);
        #pragma unroll 8
        for (int u = 0; u < 128; ++u) {
            const float w0 = Wpre0[u * 128 + c];
            const float w1 = Wpre1[u * 128 + c];
            const float4 xv = lx[sub][u];
            acc.x += w0 * xv.x;
            acc.y += w1 * xv.y;
            acc.z += w1 * xv.z;
            acc.w += w1 * xv.w;
        }
        acc.x *= inv_c; acc.y *= inv_c; acc.z *= inv_c; acc.w *= inv_c;
        h4[(size_t)n * 128 + c] = acc;
        __syncthreads();
    }
}

// ---------------- K2: radial MLP -> hmT (E, 64) row-major
__global__ __launch_bounds__(256) void mlp_kernel(const float* __restrict__ rb,
                                                  const float* __restrict__ Wm1,
                                                  const float* __restrict__ Wm2,
                                                  float* __restrict__ hmT) {
    __shared__ float4 sW1[8][16];
    __shared__ float4 sW2[64][16];
    const int tid = threadIdx.x;
    for (int i = tid; i < 8 * 16; i += 256) ((float4*)sW1)[i] = ((const float4*)Wm1)[i];
    for (int i = tid; i < 64 * 16; i += 256) ((float4*)sW2)[i] = ((const float4*)Wm2)[i];
    __syncthreads();
    const int e = blockIdx.x * 256 + tid;
    const float4* rb4 = (const float4*)(rb + (size_t)e * 8);
    const float4 r0 = rb4[0], r1 = rb4[1];
    float r[8] = {r0.x, r0.y, r0.z, r0.w, r1.x, r1.y, r1.z, r1.w};
    float h1[64];
    #pragma unroll
    for (int o4 = 0; o4 < 16; ++o4) {
        float4 a = make_float4(0.f, 0.f, 0.f, 0.f);
        #pragma unroll
        for (int k = 0; k < 8; ++k) {
            const float4 wv = sW1[k][o4];
            a.x += r[k] * wv.x; a.y += r[k] * wv.y; a.z += r[k] * wv.z; a.w += r[k] * wv.w;
        }
        h1[o4 * 4 + 0] = silu_f(a.x);
        h1[o4 * 4 + 1] = silu_f(a.y);
        h1[o4 * 4 + 2] = silu_f(a.z);
        h1[o4 * 4 + 3] = silu_f(a.w);
    }
    float4* out4 = (float4*)(hmT + (size_t)e * 64);
    #pragma unroll
    for (int o4 = 0; o4 < 16; ++o4) {
        float4 a = make_float4(0.f, 0.f, 0.f, 0.f);
        #pragma unroll 8
        for (int k = 0; k < 64; ++k) {
            const float4 wv = sW2[k][o4];
            a.x += h1[k] * wv.x; a.y += h1[k] * wv.y; a.z += h1[k] * wv.z; a.w += h1[k] * wv.w;
        }
        out4[o4] = make_float4(silu_f(a.x), silu_f(a.y), silu_f(a.z), silu_f(a.w));
    }
}

// ---------------- CSR build: count -> scan -> fill perm (edges sorted by receiver)
__global__ __launch_bounds__(256) void count_kernel(const int* __restrict__ ei,
                                                    int* __restrict__ cnt) {
    const int e = blockIdx.x * 256 + threadIdx.x;
    if (e < EE) atomicAdd(&cnt[ei[EE + e]], 1);
}

__global__ __launch_bounds__(1024) void scan_kernel(const int* __restrict__ cnt,
                                                    int* __restrict__ cur) {
    __shared__ int part[1024];
    const int t = threadIdx.x;
    const int base = t * 16;
    int local[16];
    int s = 0;
    #pragma unroll
    for (int i = 0; i < 16; ++i) {
        const int idx = base + i;
        const int v = (idx < NN) ? cnt[idx] : 0;
        local[i] = s;
        s += v;
    }
    part[t] = s;
    __syncthreads();
    for (int off = 1; off < 1024; off <<= 1) {
        int v = (t >= off) ? part[t - off] : 0;
        __syncthreads();
        part[t] += v;
        __syncthreads();
    }
    const int pre = (t == 0) ? 0 : part[t - 1];
    #pragma unroll
    for (int i = 0; i < 16; ++i) {
        const int idx = base + i;
        if (idx < NN) cur[idx] = pre + local[i];
    }
}

__global__ __launch_bounds__(256) void fill_kernel(const int* __restrict__ ei,
                                                   int* __restrict__ cur,
                                                   int* __restrict__ perm) {
    const int e = blockIdx.x * 256 + threadIdx.x;
    if (e < EE) {
        const int r = ei[EE + e];
        const int pos = atomicAdd(&cur[r], 1);
        perm[pos] = e;
    }
}

// ---------------- K3: w-GEMM over receiver-sorted edges, fused messages + run-compressed atomics
// grid: (E/128, 4 groups). Acat layout per row (1024): [A0a 128 | A0b 128 | d0:(m1a|m1b) | d1 | d2]
__global__ __launch_bounds__(256) void wmsg_kernel(const float* __restrict__ hmT,
                                                   const float* __restrict__ Wm3,
                                                   const int* __restrict__ ei,
                                                   const float4* __restrict__ sph4,
                                                   const float4* __restrict__ h4,
                                                   const int* __restrict__ perm,
                                                   float* __restrict__ Acat) {
    __shared__ float sA[64][128];
    __shared__ float sB[64][128];
    __shared__ int lp[128];
    __shared__ int ls[128];
    __shared__ int lr[128];
    __shared__ float4 lY[128];
    const int tid = threadIdx.x;
    const int g = blockIdx.y;
    const int ebase = blockIdx.x * 128;

    if (tid < 128) {
        const int p = perm[ebase + tid];
        lp[tid] = p;
        ls[tid] = ei[p];
        lr[tid] = ei[EE + p];
        lY[tid] = sph4[p];
    }
    for (int i = tid; i < 64 * 128; i += 256) {
        const int k = i >> 7, c = i & 127;
        sB[k][c] = Wm3[k * 512 + g * 128 + c];
    }
    __syncthreads();
    {
        const int i = tid & 127;
        const int half = tid >> 7;
        const float4* src4 = (const float4*)(hmT + (size_t)lp[i] * 64) + half * 8;
        #pragma unroll
        for (int q = 0; q < 8; ++q) {
            const float4 v = src4[q];
            const int k = half * 32 + q * 4;
            sA[k + 0][i] = v.x;
            sA[k + 1][i] = v.y;
            sA[k + 2][i] = v.z;
            sA[k + 3][i] = v.w;
        }
    }
    __syncthreads();

    const int tx = tid & 15, ty = tid >> 4;
    const int c0 = tx * 8, e0 = ty * 8;
    float acc[8][8];
    #pragma unroll
    for (int i = 0; i < 8; ++i)
        #pragma unroll
        for (int j = 0; j < 8; ++j) acc[i][j] = 0.f;

    #pragma unroll 4
    for (int u = 0; u < 64; ++u) {
        const float4 a0 = *(const float4*)&sA[u][e0];
        const float4 a1 = *(const float4*)&sA[u][e0 + 4];
        const float4 b0 = *(const float4*)&sB[u][c0];
        const float4 b1 = *(const float4*)&sB[u][c0 + 4];
        const float av[8] = {a0.x, a0.y, a0.z, a0.w, a1.x, a1.y, a1.z, a1.w};
        const float bv[8] = {b0.x, b0.y, b0.z, b0.w, b1.x, b1.y, b1.z, b1.w};
        #pragma unroll
        for (int i = 0; i < 8; ++i)
            #pragma unroll
            for (int j = 0; j < 8; ++j) acc[i][j] += av[i] * bv[j];
    }

    // epilogue: messages + run-compressed atomic scatter (receivers sorted within block)
    #pragma unroll
    for (int j = 0; j < 8; ++j) {
        const int c = c0 + j;
        int cr = lr[e0];
        float s0 = 0.f, s1 = 0.f, s2 = 0.f;
        #pragma unroll
        for (int i = 0; i < 8; ++i) {
            const int el = e0 + i;
            const int r = lr[el];
            if (r != cr) {
                float* arow = Acat + (size_t)cr * 1024;
                if (g == 0) atomicAdd(arow + c, s0);
                else if (g == 1) atomicAdd(arow + 128 + c, s0);
                else if (g == 2) {
                    atomicAdd(arow + 256 + c, s0);
                    atomicAdd(arow + 512 + c, s1);
                    atomicAdd(arow + 768 + c, s2);
                } else {
                    atomicAdd(arow + 384 + c, s0);
                    atomicAdd(arow + 640 + c, s1);
                    atomicAdd(arow + 896 + c, s2);
                }
                s0 = s1 = s2 = 0.f;
                cr = r;
            }
            const float w = acc[i][j];
            const float4 Y = lY[el];
            const float4 hv = h4[(size_t)ls[el] * 128 + c];
            if (g == 0) {
                s0 += w * hv.x * Y.x;
            } else if (g == 1) {
                s0 += w * (hv.y * Y.y + hv.z * Y.z + hv.w * Y.w) * 0.5773502691896258f;
            } else if (g == 2) {
                const float m = w * hv.x;
                s0 += m * Y.y; s1 += m * Y.z; s2 += m * Y.w;
            } else {
                const float m = w * Y.x;
                s0 += m * hv.y; s1 += m * hv.z; s2 += m * hv.w;
            }
        }
        float* arow = Acat + (size_t)cr * 1024;
        if (g == 0) atomicAdd(arow + c, s0);
        else if (g == 1) atomicAdd(arow + 128 + c, s0);
        else if (g == 2) {
            atomicAdd(arow + 256 + c, s0);
            atomicAdd(arow + 512 + c, s1);
            atomicAdd(arow + 768 + c, s2);
        } else {
            atomicAdd(arow + 384 + c, s0);
            atomicAdd(arow + 640 + c, s1);
            atomicAdd(arow + 896 + c, s2);
        }
    }
}

// ---------------- K4: o = Acat @ Wpost, o layout (N, 4, 128)
__global__ __launch_bounds__(256) void posto_kernel(const float* __restrict__ Acat,
                                                    const float* __restrict__ Wpost0,
                                                    const float* __restrict__ Wpost1,
                                                    float* __restrict__ o) {
    __shared__ float sA[4][256][16];
    const int tid = threadIdx.x;
    const int nb = blockIdx.x * 16;
    {
        const int n = tid & 15, idx = tid >> 4;
        const float4* row4 = (const float4*)(Acat + (size_t)(nb + n) * 1024);
        #pragma unroll
        for (int rr = 0; rr < 16; ++rr) {
            const int f4 = idx + rr * 16;
            const float4 v = row4[f4];
            const int flat = f4 * 4;
            const int d = flat >> 8;
            const int u = flat & 255;
            sA[d][u + 0][n] = v.x;
            sA[d][u + 1][n] = v.y;
            sA[d][u + 2][n] = v.z;
            sA[d][u + 3][n] = v.w;
        }
    }
    __syncthreads();
    const int c = tid & 127, half = tid >> 7, dlo = half * 2;
    const float* W0 = (half == 0) ? Wpost0 : Wpost1;
    float acc0[16], acc1[16];
    #pragma unroll
    for (int n = 0; n < 16; ++n) { acc0[n] = 0.f; acc1[n] = 0.f; }
    #pragma unroll 2
    for (int u = 0; u < 256; ++u) {
        const float w0 = W0[u * 128 + c];
        const float w1 = Wpost1[u * 128 + c];
        #pragma unroll
        for (int n = 0; n < 16; ++n) {
            acc0[n] += sA[dlo][u][n] * w0;
            acc1[n] += sA[dlo + 1][u][n] * w1;
        }
    }
    const float inv_2c = 0.0625f;
    #pragma unroll
    for (int n = 0; n < 16; ++n) {
        o[((size_t)(nb + n) * 4 + dlo) * 128 + c] = acc0[n] * inv_2c;
        o[((size_t)(nb + n) * 4 + dlo + 1) * 128 + c] = acc1[n] * inv_2c;
    }
}

// ---------------- K5: attribute contraction + final output (N, 128, 4)
// grid: (N/64, 4)
__global__ __launch_bounds__(256) void attr_kernel(const float* __restrict__ o,
                                                   const float* __restrict__ attr,
                                                   const float* __restrict__ Wa0,
                                                   const float* __restrict__ Wa1,
                                                   float* __restrict__ out) {
    __shared__ float so[128][64];
    __shared__ float sB[64][128];
    __shared__ float sat[64][10];
    const int tid = threadIdx.x;
    const int d = blockIdx.y;
    const int nb = blockIdx.x * 64;
    const float* Wa = (d == 0) ? Wa0 : Wa1;
    {
        const int n = tid >> 2, q = tid & 3;
        const float4* row4 = (const float4*)(o + ((size_t)(nb + n) * 4 + d) * 128);
        #pragma unroll
        for (int rr = 0; rr < 8; ++rr) {
            const int f4 = q * 8 + rr;
            const float4 v = row4[f4];
            const int u = f4 * 4;
            so[u + 0][n] = v.x;
            so[u + 1][n] = v.y;
            so[u + 2][n] = v.z;
            so[u + 3][n] = v.w;
        }
    }
    if (tid < 64) {
        #pragma unroll
        for (int v = 0; v < 10; ++v) sat[tid][v] = attr[(size_t)(nb + tid) * 10 + v];
    }
    __syncthreads();

    const int tx = tid & 31, ty = tid >> 5;
    const int w0 = tx * 4, n0 = ty * 8;
    float acc[8][4];
    #pragma unroll
    for (int i = 0; i < 8; ++i)
        #pragma unroll
        for (int j = 0; j < 4; ++j) acc[i][j] = 0.f;

    for (int v = 0; v < 10; ++v) {
        float satv[8];
        #pragma unroll
        for (int i = 0; i < 8; ++i) satv[i] = sat[n0 + i][v];
        for (int uc = 0; uc < 2; ++uc) {
            __syncthreads();
            for (int i = tid; i < 64 * 128; i += 256) {
                const int uu = i >> 7, w = i & 127;
                sB[uu][w] = Wa[(size_t)(uc * 64 + uu) * 1280 + v * 128 + w];
            }
            __syncthreads();
            #pragma unroll 4
            for (int uu = 0; uu < 64; ++uu) {
                const int u = uc * 64 + uu;
                const float4 a0 = *(const float4*)&so[u][n0];
                const float4 a1 = *(const float4*)&so[u][n0 + 4];
                const float4 b = *(const float4*)&sB[uu][w0];
                const float av[8] = {a0.x * satv[0], a0.y * satv[1], a0.z * satv[2], a0.w * satv[3],
                                     a1.x * satv[4], a1.y * satv[5], a1.z * satv[6], a1.w * satv[7]};
                #pragma unroll
                for (int i = 0; i < 8; ++i) {
                    acc[i][0] += av[i] * b.x;
                    acc[i][1] += av[i] * b.y;
                    acc[i][2] += av[i] * b.z;
                    acc[i][3] += av[i] * b.w;
                }
            }
        }
    }
    const float inv_ca = 0.027950849718747373f;
    #pragma unroll
    for (int i = 0; i < 8; ++i)
        #pragma unroll
        for (int j = 0; j < 4; ++j)
            out[((size_t)(nb + n0 + i) * 128 + (w0 + j)) * 4 + d] = acc[i][j] * inv_ca;
}

extern "C" void kernel_launch(void* const* d_in, const int* in_sizes, int n_in,
                              void* d_out, int out_size, void* d_ws, size_t ws_size,
                              hipStream_t stream) {
    const float* nf    = (const float*)d_in[0];
    const float* attr  = (const float*)d_in[1];
    const float* sph   = (const float*)d_in[2];
    const float* rb    = (const float*)d_in[3];
    const int*   ei    = (const int*)d_in[4];
    const float* Wpre0 = (const float*)d_in[5];
    const float* Wpre1 = (const float*)d_in[6];
    const float* Wm1   = (const float*)d_in[7];
    const float* Wm2   = (const float*)d_in[8];
    const float* Wm3   = (const float*)d_in[9];
    const float* Wpost0= (const float*)d_in[10];
    const float* Wpost1= (const float*)d_in[11];
    const float* Wa0   = (const float*)d_in[12];
    const float* Wa1   = (const float*)d_in[13];
    float* out = (float*)d_out;

    float* ws = (float*)d_ws;
    // layout (floats): h (8,192,000) | hmT (16,384,000) | Acat (16,384,000) | ints
    float4* h4  = (float4*)ws;
    float* hmT  = ws + (size_t)8192000;
    float* Acat = hmT + (size_t)16384000;
    int*   perm = (int*)(Acat + (size_t)16384000);   // 256000
    int*   cur  = perm + 256000;                      // 16384
    int*   cnt  = cur + 16384;                        // 16384
    float* o    = ws;  // alias h region (h dead after wmsg_kernel)

    hipMemsetAsync(Acat, 0, (size_t)NN * 1024 * sizeof(float), stream);
    hipMemsetAsync(cnt, 0, 16384 * sizeof(int), stream);

    pre_kernel<<<500, 256, 0, stream>>>(nf, Wpre0, Wpre1, h4);
    mlp_kernel<<<EE / 256, 256, 0, stream>>>(rb, Wm1, Wm2, hmT);
    count_kernel<<<EE / 256, 256, 0, stream>>>(ei, cnt);
    scan_kernel<<<1, 1024, 0, stream>>>(cnt, cur);
    fill_kernel<<<EE / 256, 256, 0, stream>>>(ei, cur, perm);
    wmsg_kernel<<<dim3(EE / 128, 4), 256, 0, stream>>>(hmT, Wm3, ei, (const float4*)sph, h4, perm, Acat);
    posto_kernel<<<NN / 16, 256, 0, stream>>>(Acat, Wpost0, Wpost1, o);
    attr_kernel<<<dim3(NN / 64, 4), 256, 0, stream>>>(o, attr, Wa0, Wa1, out);
}

// Round 3
// 1210.129 us; speedup vs baseline: 6.3046x; 2.8482x over previous
//
#include <hip/hip_runtime.h>
#include <hip/hip_bf16.h>

#define NN 16000
#define CC 128
#define EE 256000
#define AA 10

__device__ __forceinline__ float silu_f(float x) {
    return x / (1.0f + __expf(-x));
}

__device__ __forceinline__ float bf2f(unsigned short u) {
    unsigned int x = ((unsigned int)u) << 16;
    float f;
    __builtin_memcpy(&f, &x, 4);
    return f;
}

__device__ __forceinline__ unsigned short f2bf(float f) {
    __hip_bfloat16 b = __float2bfloat16(f);
    unsigned short u;
    __builtin_memcpy(&u, &b, 2);
    return u;
}

// ---------------- K1: h0/h1 pre-linears -> h (N,128) float4 [h0, h1x, h1y, h1z]
__global__ __launch_bounds__(256) void pre_kernel(const float* __restrict__ nf,
                                                  const float* __restrict__ Wpre0,
                                                  const float* __restrict__ Wpre1,
                                                  float4* __restrict__ h4) {
    __shared__ float4 lx[2][CC];
    const int c = threadIdx.x & 127;
    const int sub = threadIdx.x >> 7;
    const float inv_c = 0.08838834764831843f;
    const int base = blockIdx.x * 32;
    for (int it = 0; it < 16; ++it) {
        const int n = base + it * 2 + sub;
        const float* row = nf + (size_t)n * 512;
        lx[sub][c] = make_float4(row[c], row[128 + 3 * c], row[128 + 3 * c + 1], row[128 + 3 * c + 2]);
        __syncthreads();
        float4 acc = make_float4(0.f, 0.f, 0.f, 0.f);
        #pragma unroll 8
        for (int u = 0; u < 128; ++u) {
            const float w0 = Wpre0[u * 128 + c];
            const float w1 = Wpre1[u * 128 + c];
            const float4 xv = lx[sub][u];
            acc.x += w0 * xv.x;
            acc.y += w1 * xv.y;
            acc.z += w1 * xv.z;
            acc.w += w1 * xv.w;
        }
        acc.x *= inv_c; acc.y *= inv_c; acc.z *= inv_c; acc.w *= inv_c;
        h4[(size_t)n * 128 + c] = acc;
        __syncthreads();
    }
}

// ---------------- CSR build: count -> scan -> fill perm (edges sorted by receiver)
__global__ __launch_bounds__(256) void count_kernel(const int* __restrict__ ei,
                                                    int* __restrict__ cnt) {
    const int e = blockIdx.x * 256 + threadIdx.x;
    if (e < EE) atomicAdd(&cnt[ei[EE + e]], 1);
}

__global__ __launch_bounds__(1024) void scan_kernel(const int* __restrict__ cnt,
                                                    int* __restrict__ cur) {
    __shared__ int part[1024];
    const int t = threadIdx.x;
    const int base = t * 16;
    int local[16];
    int s = 0;
    #pragma unroll
    for (int i = 0; i < 16; ++i) {
        const int idx = base + i;
        const int v = (idx < NN) ? cnt[idx] : 0;
        local[i] = s;
        s += v;
    }
    part[t] = s;
    __syncthreads();
    for (int off = 1; off < 1024; off <<= 1) {
        int v = (t >= off) ? part[t - off] : 0;
        __syncthreads();
        part[t] += v;
        __syncthreads();
    }
    const int pre = (t == 0) ? 0 : part[t - 1];
    #pragma unroll
    for (int i = 0; i < 16; ++i) {
        const int idx = base + i;
        if (idx < NN) cur[idx] = pre + local[i];
    }
}

__global__ __launch_bounds__(256) void fill_kernel(const int* __restrict__ ei,
                                                   int* __restrict__ cur,
                                                   int* __restrict__ perm) {
    const int e = blockIdx.x * 256 + threadIdx.x;
    if (e < EE) {
        const int r = ei[EE + e];
        const int pos = atomicAdd(&cur[r], 1);
        perm[pos] = e;
    }
}

// ---------------- gather edge metadata into sorted order
__global__ __launch_bounds__(256) void gather_kernel(const int* __restrict__ perm,
                                                     const int* __restrict__ ei,
                                                     const float4* __restrict__ sph4,
                                                     int* __restrict__ ss,
                                                     int* __restrict__ rs,
                                                     float4* __restrict__ Ys) {
    const int e = blockIdx.x * 256 + threadIdx.x;
    const int p = perm[e];
    ss[e] = ei[p];
    rs[e] = ei[EE + p];
    Ys[e] = sph4[p];
}

// ---------------- K2: radial MLP in sorted order -> hmS (E,64) bf16 row-major
__global__ __launch_bounds__(256) void mlp_kernel(const float* __restrict__ rb,
                                                  const float* __restrict__ Wm1,
                                                  const float* __restrict__ Wm2,
                                                  const int* __restrict__ perm,
                                                  unsigned short* __restrict__ hmS) {
    __shared__ float4 sW1[8][16];
    __shared__ float4 sW2[64][16];
    __shared__ unsigned short sH[256][64];
    const int tid = threadIdx.x;
    for (int i = tid; i < 8 * 16; i += 256) ((float4*)sW1)[i] = ((const float4*)Wm1)[i];
    for (int i = tid; i < 64 * 16; i += 256) ((float4*)sW2)[i] = ((const float4*)Wm2)[i];
    __syncthreads();
    const int e = blockIdx.x * 256 + tid;
    const int p = perm[e];
    const float4* rb4 = (const float4*)(rb + (size_t)p * 8);
    const float4 r0 = rb4[0], r1 = rb4[1];
    float r[8] = {r0.x, r0.y, r0.z, r0.w, r1.x, r1.y, r1.z, r1.w};
    float h1[64];
    #pragma unroll
    for (int o4 = 0; o4 < 16; ++o4) {
        float4 a = make_float4(0.f, 0.f, 0.f, 0.f);
        #pragma unroll
        for (int k = 0; k < 8; ++k) {
            const float4 wv = sW1[k][o4];
            a.x += r[k] * wv.x; a.y += r[k] * wv.y; a.z += r[k] * wv.z; a.w += r[k] * wv.w;
        }
        h1[o4 * 4 + 0] = silu_f(a.x);
        h1[o4 * 4 + 1] = silu_f(a.y);
        h1[o4 * 4 + 2] = silu_f(a.z);
        h1[o4 * 4 + 3] = silu_f(a.w);
    }
    #pragma unroll
    for (int o4 = 0; o4 < 16; ++o4) {
        float4 a = make_float4(0.f, 0.f, 0.f, 0.f);
        #pragma unroll 8
        for (int k = 0; k < 64; ++k) {
            const float4 wv = sW2[k][o4];
            a.x += h1[k] * wv.x; a.y += h1[k] * wv.y; a.z += h1[k] * wv.z; a.w += h1[k] * wv.w;
        }
        sH[tid][o4 * 4 + 0] = f2bf(silu_f(a.x));
        sH[tid][o4 * 4 + 1] = f2bf(silu_f(a.y));
        sH[tid][o4 * 4 + 2] = f2bf(silu_f(a.z));
        sH[tid][o4 * 4 + 3] = f2bf(silu_f(a.w));
    }
    __syncthreads();
    uint4* g4 = (uint4*)(hmS + (size_t)blockIdx.x * 256 * 64);
    const uint4* s4 = (const uint4*)sH;
    for (int i = tid; i < 2048; i += 256) g4[i] = s4[i];
}

// ---------------- K3: single-pass w-GEMM over sorted edges, fused messages + run-compressed atomics
// Acat row layout (1024): [A0a 128 | A0b 128 | d0:(m1a|m1b) | d1 | d2]
__global__ __launch_bounds__(256) void wmsg_kernel(const unsigned short* __restrict__ hmS,
                                                   const float* __restrict__ Wm3,
                                                   const int* __restrict__ ss,
                                                   const int* __restrict__ rs,
                                                   const float4* __restrict__ Ys,
                                                   const float4* __restrict__ h4,
                                                   float* __restrict__ Acat) {
    __shared__ float sA[64][32];
    __shared__ float sB[8][512];
    __shared__ int lss[32];
    __shared__ int lrs[32];
    __shared__ float4 lY[32];
    const int tid = threadIdx.x;
    const int ebase = blockIdx.x * 32;

    if (tid < 32) {
        lss[tid] = ss[ebase + tid];
        lrs[tid] = rs[ebase + tid];
        lY[tid] = Ys[ebase + tid];
    }
    {
        // 32 rows x 128B bf16 = 256 uint4, one per thread, fully coalesced
        const uint4 v = ((const uint4*)hmS)[(size_t)ebase * 8 + tid];
        const int e = tid >> 3, q = tid & 7;
        const unsigned short* us = (const unsigned short*)&v;
        #pragma unroll
        for (int j = 0; j < 8; ++j) sA[q * 8 + j][e] = bf2f(us[j]);
    }

    const int c = tid & 127, eh = tid >> 7;
    float acc[16][4];
    #pragma unroll
    for (int e = 0; e < 16; ++e)
        #pragma unroll
        for (int g = 0; g < 4; ++g) acc[e][g] = 0.f;

    for (int kk = 0; kk < 8; ++kk) {
        __syncthreads();
        {
            const float4* w4 = (const float4*)(Wm3 + (size_t)kk * 8 * 512);
            #pragma unroll
            for (int t = 0; t < 4; ++t) {
                const int i = tid + t * 256;
                ((float4*)sB)[i] = w4[i];
            }
        }
        __syncthreads();
        #pragma unroll
        for (int k8 = 0; k8 < 8; ++k8) {
            const int k = kk * 8 + k8;
            const float b0 = sB[k8][c];
            const float b1 = sB[k8][128 + c];
            const float b2 = sB[k8][256 + c];
            const float b3 = sB[k8][384 + c];
            const float4 a0 = *(const float4*)&sA[k][eh * 16];
            const float4 a1 = *(const float4*)&sA[k][eh * 16 + 4];
            const float4 a2 = *(const float4*)&sA[k][eh * 16 + 8];
            const float4 a3 = *(const float4*)&sA[k][eh * 16 + 12];
            const float av[16] = {a0.x, a0.y, a0.z, a0.w, a1.x, a1.y, a1.z, a1.w,
                                  a2.x, a2.y, a2.z, a2.w, a3.x, a3.y, a3.z, a3.w};
            #pragma unroll
            for (int e = 0; e < 16; ++e) {
                acc[e][0] += av[e] * b0;
                acc[e][1] += av[e] * b1;
                acc[e][2] += av[e] * b2;
                acc[e][3] += av[e] * b3;
            }
        }
    }

    // epilogue: all 4 message groups per (edge,c), h row read ONCE per edge
    float s0 = 0.f, s1 = 0.f, s2 = 0.f, s3 = 0.f, s4v = 0.f, s5 = 0.f, s6 = 0.f, s7 = 0.f;
    int cr = lrs[eh * 16];
    #pragma unroll
    for (int e = 0; e < 16; ++e) {
        const int el = eh * 16 + e;
        const int r = lrs[el];
        if (r != cr) {
            float* arow = Acat + (size_t)cr * 1024;
            atomicAdd(arow + c, s0);
            atomicAdd(arow + 128 + c, s1);
            atomicAdd(arow + 256 + c, s2);
            atomicAdd(arow + 512 + c, s3);
            atomicAdd(arow + 768 + c, s4v);
            atomicAdd(arow + 384 + c, s5);
            atomicAdd(arow + 640 + c, s6);
            atomicAdd(arow + 896 + c, s7);
            s0 = s1 = s2 = s3 = s4v = s5 = s6 = s7 = 0.f;
            cr = r;
        }
        const float4 Y = lY[el];
        const float4 hv = h4[(size_t)lss[el] * 128 + c];
        const float w0 = acc[e][0], w1 = acc[e][1], w2 = acc[e][2], w3 = acc[e][3];
        s0 += w0 * hv.x * Y.x;
        s1 += w1 * (hv.y * Y.y + hv.z * Y.z + hv.w * Y.w) * 0.5773502691896258f;
        const float m = w2 * hv.x;
        s2 += m * Y.y; s3 += m * Y.z; s4v += m * Y.w;
        const float m2 = w3 * Y.x;
        s5 += m2 * hv.y; s6 += m2 * hv.z; s7 += m2 * hv.w;
    }
    {
        float* arow = Acat + (size_t)cr * 1024;
        atomicAdd(arow + c, s0);
        atomicAdd(arow + 128 + c, s1);
        atomicAdd(arow + 256 + c, s2);
        atomicAdd(arow + 512 + c, s3);
        atomicAdd(arow + 768 + c, s4v);
        atomicAdd(arow + 384 + c, s5);
        atomicAdd(arow + 640 + c, s6);
        atomicAdd(arow + 896 + c, s7);
    }
}

// ---------------- K4: o = Acat @ Wpost, o layout (N, 4, 128)
__global__ __launch_bounds__(256) void posto_kernel(const float* __restrict__ Acat,
                                                    const float* __restrict__ Wpost0,
                                                    const float* __restrict__ Wpost1,
                                                    float* __restrict__ o) {
    __shared__ float sA[4][256][16];
    const int tid = threadIdx.x;
    const int nb = blockIdx.x * 16;
    {
        const int n = tid & 15, idx = tid >> 4;
        const float4* row4 = (const float4*)(Acat + (size_t)(nb + n) * 1024);
        #pragma unroll
        for (int rr = 0; rr < 16; ++rr) {
            const int f4 = idx + rr * 16;
            const float4 v = row4[f4];
            const int flat = f4 * 4;
            const int d = flat >> 8;
            const int u = flat & 255;
            sA[d][u + 0][n] = v.x;
            sA[d][u + 1][n] = v.y;
            sA[d][u + 2][n] = v.z;
            sA[d][u + 3][n] = v.w;
        }
    }
    __syncthreads();
    const int c = tid & 127, half = tid >> 7, dlo = half * 2;
    const float* W0 = (half == 0) ? Wpost0 : Wpost1;
    float acc0[16], acc1[16];
    #pragma unroll
    for (int n = 0; n < 16; ++n) { acc0[n] = 0.f; acc1[n] = 0.f; }
    #pragma unroll 2
    for (int u = 0; u < 256; ++u) {
        const float w0 = W0[u * 128 + c];
        const float w1 = Wpost1[u * 128 + c];
        #pragma unroll
        for (int n = 0; n < 16; ++n) {
            acc0[n] += sA[dlo][u][n] * w0;
            acc1[n] += sA[dlo + 1][u][n] * w1;
        }
    }
    const float inv_2c = 0.0625f;
    #pragma unroll
    for (int n = 0; n < 16; ++n) {
        o[((size_t)(nb + n) * 4 + dlo) * 128 + c] = acc0[n] * inv_2c;
        o[((size_t)(nb + n) * 4 + dlo + 1) * 128 + c] = acc1[n] * inv_2c;
    }
}

// ---------------- K5: attribute contraction + final output (N, 128, 4)
__global__ __launch_bounds__(256) void attr_kernel(const float* __restrict__ o,
                                                   const float* __restrict__ attr,
                                                   const float* __restrict__ Wa0,
                                                   const float* __restrict__ Wa1,
                                                   float* __restrict__ out) {
    __shared__ float so[128][64];
    __shared__ float sB[64][128];
    __shared__ float sat[64][10];
    const int tid = threadIdx.x;
    const int d = blockIdx.y;
    const int nb = blockIdx.x * 64;
    const float* Wa = (d == 0) ? Wa0 : Wa1;
    {
        const int n = tid >> 2, q = tid & 3;
        const float4* row4 = (const float4*)(o + ((size_t)(nb + n) * 4 + d) * 128);
        #pragma unroll
        for (int rr = 0; rr < 8; ++rr) {
            const int f4 = q * 8 + rr;
            const float4 v = row4[f4];
            const int u = f4 * 4;
            so[u + 0][n] = v.x;
            so[u + 1][n] = v.y;
            so[u + 2][n] = v.z;
            so[u + 3][n] = v.w;
        }
    }
    if (tid < 64) {
        #pragma unroll
        for (int v = 0; v < 10; ++v) sat[tid][v] = attr[(size_t)(nb + tid) * 10 + v];
    }
    __syncthreads();

    const int tx = tid & 31, ty = tid >> 5;
    const int w0 = tx * 4, n0 = ty * 8;
    float acc[8][4];
    #pragma unroll
    for (int i = 0; i < 8; ++i)
        #pragma unroll
        for (int j = 0; j < 4; ++j) acc[i][j] = 0.f;

    for (int v = 0; v < 10; ++v) {
        float satv[8];
        #pragma unroll
        for (int i = 0; i < 8; ++i) satv[i] = sat[n0 + i][v];
        for (int uc = 0; uc < 2; ++uc) {
            __syncthreads();
            for (int i = tid; i < 64 * 128; i += 256) {
                const int uu = i >> 7, w = i & 127;
                sB[uu][w] = Wa[(size_t)(uc * 64 + uu) * 1280 + v * 128 + w];
            }
            __syncthreads();
            #pragma unroll 4
            for (int uu = 0; uu < 64; ++uu) {
                const int u = uc * 64 + uu;
                const float4 a0 = *(const float4*)&so[u][n0];
                const float4 a1 = *(const float4*)&so[u][n0 + 4];
                const float4 b = *(const float4*)&sB[uu][w0];
                const float av[8] = {a0.x * satv[0], a0.y * satv[1], a0.z * satv[2], a0.w * satv[3],
                                     a1.x * satv[4], a1.y * satv[5], a1.z * satv[6], a1.w * satv[7]};
                #pragma unroll
                for (int i = 0; i < 8; ++i) {
                    acc[i][0] += av[i] * b.x;
                    acc[i][1] += av[i] * b.y;
                    acc[i][2] += av[i] * b.z;
                    acc[i][3] += av[i] * b.w;
                }
            }
        }
    }
    const float inv_ca = 0.027950849718747373f;
    #pragma unroll
    for (int i = 0; i < 8; ++i)
        #pragma unroll
        for (int j = 0; j < 4; ++j)
            out[((size_t)(nb + n0 + i) * 128 + (w0 + j)) * 4 + d] = acc[i][j] * inv_ca;
}

extern "C" void kernel_launch(void* const* d_in, const int* in_sizes, int n_in,
                              void* d_out, int out_size, void* d_ws, size_t ws_size,
                              hipStream_t stream) {
    const float* nf    = (const float*)d_in[0];
    const float* attr  = (const float*)d_in[1];
    const float* sph   = (const float*)d_in[2];
    const float* rb    = (const float*)d_in[3];
    const int*   ei    = (const int*)d_in[4];
    const float* Wpre0 = (const float*)d_in[5];
    const float* Wpre1 = (const float*)d_in[6];
    const float* Wm1   = (const float*)d_in[7];
    const float* Wm2   = (const float*)d_in[8];
    const float* Wm3   = (const float*)d_in[9];
    const float* Wpost0= (const float*)d_in[10];
    const float* Wpost1= (const float*)d_in[11];
    const float* Wa0   = (const float*)d_in[12];
    const float* Wa1   = (const float*)d_in[13];
    float* out = (float*)d_out;

    float* ws = (float*)d_ws;
    // layout (float units):
    // h4:   [0, 8192000)            32 MB  (N,128) float4
    // hmS:  [8192000, 16384000)     32 MB  (E,64) bf16
    // Acat: [16384000, 32768000)    64 MB  (N,1024) f32
    // ints + Ys after
    float4* h4 = (float4*)ws;
    unsigned short* hmS = (unsigned short*)(ws + (size_t)8192000);
    float* Acat = ws + (size_t)16384000;
    int* perm = (int*)(Acat + (size_t)16384000);  // 256000
    int* cur  = perm + 256000;                     // 16384
    int* cnt  = cur + 16384;                       // 16384
    int* ss   = cnt + 16384;                       // 256000
    int* rs   = ss + 256000;                       // 256000
    float4* Ys = (float4*)(rs + 256000);           // 256000 float4 (16B aligned)
    float* o = ws;  // (N,4,128) = 8192000 f, aliases h4 (dead after wmsg)

    hipMemsetAsync(Acat, 0, (size_t)NN * 1024 * sizeof(float), stream);
    hipMemsetAsync(cnt, 0, 16384 * sizeof(int), stream);

    pre_kernel<<<500, 256, 0, stream>>>(nf, Wpre0, Wpre1, h4);
    count_kernel<<<EE / 256, 256, 0, stream>>>(ei, cnt);
    scan_kernel<<<1, 1024, 0, stream>>>(cnt, cur);
    fill_kernel<<<EE / 256, 256, 0, stream>>>(ei, cur, perm);
    gather_kernel<<<EE / 256, 256, 0, stream>>>(perm, ei, (const float4*)sph, ss, rs, Ys);
    mlp_kernel<<<EE / 256, 256, 0, stream>>>(rb, Wm1, Wm2, perm, hmS);
    wmsg_kernel<<<EE / 32, 256, 0, stream>>>(hmS, Wm3, ss, rs, Ys, h4, Acat);
    posto_kernel<<<NN / 16, 256, 0, stream>>>(Acat, Wpost0, Wpost1, o);
    attr_kernel<<<dim3(NN / 64, 4), 256, 0, stream>>>(o, attr, Wa0, Wa1, out);
}

// Round 4
// 867.917 us; speedup vs baseline: 8.7904x; 1.3943x over previous
//
#include <hip/hip_runtime.h>
#include <hip/hip_bf16.h>

#define NN 16000
#define CC 128
#define EE 256000
#define AA 10

typedef short short8_t __attribute__((ext_vector_type(8)));
typedef float f32x4 __attribute__((ext_vector_type(4)));
typedef unsigned short u16x4 __attribute__((ext_vector_type(4)));

__device__ __forceinline__ float silu_f(float x) {
    return x / (1.0f + __expf(-x));
}

__device__ __forceinline__ float bf2f(unsigned short u) {
    unsigned int x = ((unsigned int)u) << 16;
    float f;
    __builtin_memcpy(&f, &x, 4);
    return f;
}

__device__ __forceinline__ unsigned short f2bf(float f) {
    __hip_bfloat16 b = __float2bfloat16(f);
    unsigned short u;
    __builtin_memcpy(&u, &b, 2);
    return u;
}

// ---------------- K1: h0/h1 pre-linears -> h (N,128) float4 [h0, h1x, h1y, h1z]
__global__ __launch_bounds__(256) void pre_kernel(const float* __restrict__ nf,
                                                  const float* __restrict__ Wpre0,
                                                  const float* __restrict__ Wpre1,
                                                  float4* __restrict__ h4) {
    __shared__ float4 lx[2][CC];
    const int c = threadIdx.x & 127;
    const int sub = threadIdx.x >> 7;
    const float inv_c = 0.08838834764831843f;
    const int base = blockIdx.x * 32;
    for (int it = 0; it < 16; ++it) {
        const int n = base + it * 2 + sub;
        const float* row = nf + (size_t)n * 512;
        lx[sub][c] = make_float4(row[c], row[128 + 3 * c], row[128 + 3 * c + 1], row[128 + 3 * c + 2]);
        __syncthreads();
        float4 acc = make_float4(0.f, 0.f, 0.f, 0.f);
        #pragma unroll 8
        for (int u = 0; u < 128; ++u) {
            const float w0 = Wpre0[u * 128 + c];
            const float w1 = Wpre1[u * 128 + c];
            const float4 xv = lx[sub][u];
            acc.x += w0 * xv.x;
            acc.y += w1 * xv.y;
            acc.z += w1 * xv.z;
            acc.w += w1 * xv.w;
        }
        acc.x *= inv_c; acc.y *= inv_c; acc.z *= inv_c; acc.w *= inv_c;
        h4[(size_t)n * 128 + c] = acc;
        __syncthreads();
    }
}

// ---------------- CSR build: count -> scan -> fill perm (edges sorted by receiver)
__global__ __launch_bounds__(256) void count_kernel(const int* __restrict__ ei,
                                                    int* __restrict__ cnt) {
    const int e = blockIdx.x * 256 + threadIdx.x;
    if (e < EE) atomicAdd(&cnt[ei[EE + e]], 1);
}

__global__ __launch_bounds__(1024) void scan_kernel(const int* __restrict__ cnt,
                                                    int* __restrict__ cur) {
    __shared__ int part[1024];
    const int t = threadIdx.x;
    const int base = t * 16;
    int local[16];
    int s = 0;
    #pragma unroll
    for (int i = 0; i < 16; ++i) {
        const int idx = base + i;
        const int v = (idx < NN) ? cnt[idx] : 0;
        local[i] = s;
        s += v;
    }
    part[t] = s;
    __syncthreads();
    for (int off = 1; off < 1024; off <<= 1) {
        int v = (t >= off) ? part[t - off] : 0;
        __syncthreads();
        part[t] += v;
        __syncthreads();
    }
    const int pre = (t == 0) ? 0 : part[t - 1];
    #pragma unroll
    for (int i = 0; i < 16; ++i) {
        const int idx = base + i;
        if (idx < NN) cur[idx] = pre + local[i];
    }
}

__global__ __launch_bounds__(256) void fill_kernel(const int* __restrict__ ei,
                                                   int* __restrict__ cur,
                                                   int* __restrict__ perm) {
    const int e = blockIdx.x * 256 + threadIdx.x;
    if (e < EE) {
        const int r = ei[EE + e];
        const int pos = atomicAdd(&cur[r], 1);
        perm[pos] = e;
    }
}

// ---------------- gather edge metadata into sorted order
__global__ __launch_bounds__(256) void gather_kernel(const int* __restrict__ perm,
                                                     const int* __restrict__ ei,
                                                     const float4* __restrict__ sph4,
                                                     int* __restrict__ ss,
                                                     int* __restrict__ rs,
                                                     float4* __restrict__ Ys) {
    const int e = blockIdx.x * 256 + threadIdx.x;
    const int p = perm[e];
    ss[e] = ei[p];
    rs[e] = ei[EE + p];
    Ys[e] = sph4[p];
}

// ---------------- K2: radial MLP in sorted order -> hmS (E,64) bf16 row-major
__global__ __launch_bounds__(256) void mlp_kernel(const float* __restrict__ rb,
                                                  const float* __restrict__ Wm1,
                                                  const float* __restrict__ Wm2,
                                                  const int* __restrict__ perm,
                                                  unsigned short* __restrict__ hmS) {
    __shared__ float4 sW1[8][16];
    __shared__ float4 sW2[64][16];
    __shared__ unsigned short sH[256][64];
    const int tid = threadIdx.x;
    for (int i = tid; i < 8 * 16; i += 256) ((float4*)sW1)[i] = ((const float4*)Wm1)[i];
    for (int i = tid; i < 64 * 16; i += 256) ((float4*)sW2)[i] = ((const float4*)Wm2)[i];
    __syncthreads();
    const int e = blockIdx.x * 256 + tid;
    const int p = perm[e];
    const float4* rb4 = (const float4*)(rb + (size_t)p * 8);
    const float4 r0 = rb4[0], r1 = rb4[1];
    float r[8] = {r0.x, r0.y, r0.z, r0.w, r1.x, r1.y, r1.z, r1.w};
    float h1[64];
    #pragma unroll
    for (int o4 = 0; o4 < 16; ++o4) {
        float4 a = make_float4(0.f, 0.f, 0.f, 0.f);
        #pragma unroll
        for (int k = 0; k < 8; ++k) {
            const float4 wv = sW1[k][o4];
            a.x += r[k] * wv.x; a.y += r[k] * wv.y; a.z += r[k] * wv.z; a.w += r[k] * wv.w;
        }
        h1[o4 * 4 + 0] = silu_f(a.x);
        h1[o4 * 4 + 1] = silu_f(a.y);
        h1[o4 * 4 + 2] = silu_f(a.z);
        h1[o4 * 4 + 3] = silu_f(a.w);
    }
    #pragma unroll
    for (int o4 = 0; o4 < 16; ++o4) {
        float4 a = make_float4(0.f, 0.f, 0.f, 0.f);
        #pragma unroll 8
        for (int k = 0; k < 64; ++k) {
            const float4 wv = sW2[k][o4];
            a.x += h1[k] * wv.x; a.y += h1[k] * wv.y; a.z += h1[k] * wv.z; a.w += h1[k] * wv.w;
        }
        sH[tid][o4 * 4 + 0] = f2bf(silu_f(a.x));
        sH[tid][o4 * 4 + 1] = f2bf(silu_f(a.y));
        sH[tid][o4 * 4 + 2] = f2bf(silu_f(a.z));
        sH[tid][o4 * 4 + 3] = f2bf(silu_f(a.w));
    }
    __syncthreads();
    uint4* g4 = (uint4*)(hmS + (size_t)blockIdx.x * 256 * 64);
    const uint4* s4 = (const uint4*)sH;
    for (int i = tid; i < 2048; i += 256) g4[i] = s4[i];
}

// ---------------- K3: single-pass w-GEMM over sorted edges, fused messages + run-compressed atomics
// Acat row layout (1024): [A0a 128 | A0b 128 | d0:(m1a|m1b) | d1 | d2]
__global__ __launch_bounds__(256) void wmsg_kernel(const unsigned short* __restrict__ hmS,
                                                   const float* __restrict__ Wm3,
                                                   const int* __restrict__ ss,
                                                   const int* __restrict__ rs,
                                                   const float4* __restrict__ Ys,
                                                   const float4* __restrict__ h4,
                                                   float* __restrict__ Acat) {
    __shared__ float sA[64][32];
    __shared__ float sB[8][512];
    __shared__ int lss[32];
    __shared__ int lrs[32];
    __shared__ float4 lY[32];
    const int tid = threadIdx.x;
    const int ebase = blockIdx.x * 32;

    if (tid < 32) {
        lss[tid] = ss[ebase + tid];
        lrs[tid] = rs[ebase + tid];
        lY[tid] = Ys[ebase + tid];
    }
    {
        const uint4 v = ((const uint4*)hmS)[(size_t)ebase * 8 + tid];
        const int e = tid >> 3, q = tid & 7;
        const unsigned short* us = (const unsigned short*)&v;
        #pragma unroll
        for (int j = 0; j < 8; ++j) sA[q * 8 + j][e] = bf2f(us[j]);
    }

    const int c = tid & 127, eh = tid >> 7;
    float acc[16][4];
    #pragma unroll
    for (int e = 0; e < 16; ++e)
        #pragma unroll
        for (int g = 0; g < 4; ++g) acc[e][g] = 0.f;

    for (int kk = 0; kk < 8; ++kk) {
        __syncthreads();
        {
            const float4* w4 = (const float4*)(Wm3 + (size_t)kk * 8 * 512);
            #pragma unroll
            for (int t = 0; t < 4; ++t) {
                const int i = tid + t * 256;
                ((float4*)sB)[i] = w4[i];
            }
        }
        __syncthreads();
        #pragma unroll
        for (int k8 = 0; k8 < 8; ++k8) {
            const int k = kk * 8 + k8;
            const float b0 = sB[k8][c];
            const float b1 = sB[k8][128 + c];
            const float b2 = sB[k8][256 + c];
            const float b3 = sB[k8][384 + c];
            const float4 a0 = *(const float4*)&sA[k][eh * 16];
            const float4 a1 = *(const float4*)&sA[k][eh * 16 + 4];
            const float4 a2 = *(const float4*)&sA[k][eh * 16 + 8];
            const float4 a3 = *(const float4*)&sA[k][eh * 16 + 12];
            const float av[16] = {a0.x, a0.y, a0.z, a0.w, a1.x, a1.y, a1.z, a1.w,
                                  a2.x, a2.y, a2.z, a2.w, a3.x, a3.y, a3.z, a3.w};
            #pragma unroll
            for (int e = 0; e < 16; ++e) {
                acc[e][0] += av[e] * b0;
                acc[e][1] += av[e] * b1;
                acc[e][2] += av[e] * b2;
                acc[e][3] += av[e] * b3;
            }
        }
    }

    float s0 = 0.f, s1 = 0.f, s2 = 0.f, s3 = 0.f, s4v = 0.f, s5 = 0.f, s6 = 0.f, s7 = 0.f;
    int cr = lrs[eh * 16];
    #pragma unroll
    for (int e = 0; e < 16; ++e) {
        const int el = eh * 16 + e;
        const int r = lrs[el];
        if (r != cr) {
            float* arow = Acat + (size_t)cr * 1024;
            atomicAdd(arow + c, s0);
            atomicAdd(arow + 128 + c, s1);
            atomicAdd(arow + 256 + c, s2);
            atomicAdd(arow + 512 + c, s3);
            atomicAdd(arow + 768 + c, s4v);
            atomicAdd(arow + 384 + c, s5);
            atomicAdd(arow + 640 + c, s6);
            atomicAdd(arow + 896 + c, s7);
            s0 = s1 = s2 = s3 = s4v = s5 = s6 = s7 = 0.f;
            cr = r;
        }
        const float4 Y = lY[el];
        const float4 hv = h4[(size_t)lss[el] * 128 + c];
        const float w0 = acc[e][0], w1 = acc[e][1], w2 = acc[e][2], w3 = acc[e][3];
        s0 += w0 * hv.x * Y.x;
        s1 += w1 * (hv.y * Y.y + hv.z * Y.z + hv.w * Y.w) * 0.5773502691896258f;
        const float m = w2 * hv.x;
        s2 += m * Y.y; s3 += m * Y.z; s4v += m * Y.w;
        const float m2 = w3 * Y.x;
        s5 += m2 * hv.y; s6 += m2 * hv.z; s7 += m2 * hv.w;
    }
    {
        float* arow = Acat + (size_t)cr * 1024;
        atomicAdd(arow + c, s0);
        atomicAdd(arow + 128 + c, s1);
        atomicAdd(arow + 256 + c, s2);
        atomicAdd(arow + 512 + c, s3);
        atomicAdd(arow + 768 + c, s4v);
        atomicAdd(arow + 384 + c, s5);
        atomicAdd(arow + 640 + c, s6);
        atomicAdd(arow + 896 + c, s7);
    }
}

// ---------------- K4: o = Acat @ Wpost, o layout (N, 4, 128)
__global__ __launch_bounds__(256) void posto_kernel(const float* __restrict__ Acat,
                                                    const float* __restrict__ Wpost0,
                                                    const float* __restrict__ Wpost1,
                                                    float* __restrict__ o) {
    __shared__ float sA[4][256][16];
    const int tid = threadIdx.x;
    const int nb = blockIdx.x * 16;
    {
        const int n = tid & 15, idx = tid >> 4;
        const float4* row4 = (const float4*)(Acat + (size_t)(nb + n) * 1024);
        #pragma unroll
        for (int rr = 0; rr < 16; ++rr) {
            const int f4 = idx + rr * 16;
            const float4 v = row4[f4];
            const int flat = f4 * 4;
            const int d = flat >> 8;
            const int u = flat & 255;
            sA[d][u + 0][n] = v.x;
            sA[d][u + 1][n] = v.y;
            sA[d][u + 2][n] = v.z;
            sA[d][u + 3][n] = v.w;
        }
    }
    __syncthreads();
    const int c = tid & 127, half = tid >> 7, dlo = half * 2;
    const float* W0 = (half == 0) ? Wpost0 : Wpost1;
    float acc0[16], acc1[16];
    #pragma unroll
    for (int n = 0; n < 16; ++n) { acc0[n] = 0.f; acc1[n] = 0.f; }
    #pragma unroll 2
    for (int u = 0; u < 256; ++u) {
        const float w0 = W0[u * 128 + c];
        const float w1 = Wpost1[u * 128 + c];
        #pragma unroll
        for (int n = 0; n < 16; ++n) {
            acc0[n] += sA[dlo][u][n] * w0;
            acc1[n] += sA[dlo + 1][u][n] * w1;
        }
    }
    const float inv_2c = 0.0625f;
    #pragma unroll
    for (int n = 0; n < 16; ++n) {
        o[((size_t)(nb + n) * 4 + dlo) * 128 + c] = acc0[n] * inv_2c;
        o[((size_t)(nb + n) * 4 + dlo + 1) * 128 + c] = acc1[n] * inv_2c;
    }
}

// ---------------- WaT: one-time transpose Wa(u,v,w) -> WaT[arr][v][w][u] bf16
__global__ __launch_bounds__(256) void watT_kernel(const float* __restrict__ Wa0,
                                                   const float* __restrict__ Wa1,
                                                   unsigned short* __restrict__ WaT) {
    __shared__ unsigned short tile[128][129];
    const int tid = threadIdx.x;
    const int v = blockIdx.x;
    const int arr = blockIdx.y;
    const float* Wa = (arr == 0) ? Wa0 : Wa1;
    {
        const int u = tid >> 1, half = tid & 1;
        const float4* src = (const float4*)(Wa + ((size_t)u * AA + v) * 128 + half * 64);
        #pragma unroll
        for (int j = 0; j < 16; ++j) {
            const float4 val = src[j];
            const int w = half * 64 + j * 4;
            tile[w + 0][u] = f2bf(val.x);
            tile[w + 1][u] = f2bf(val.y);
            tile[w + 2][u] = f2bf(val.z);
            tile[w + 3][u] = f2bf(val.w);
        }
    }
    __syncthreads();
    {
        const int w = tid >> 1, half = tid & 1;
        unsigned short* dst = WaT + (size_t)arr * 163840 + (size_t)v * 16384 + (size_t)w * 128;
        #pragma unroll
        for (int j = 0; j < 8; ++j) {
            const int u0 = half * 64 + j * 8;
            union { unsigned short s[8]; uint4 q; } pk;
            #pragma unroll
            for (int k = 0; k < 8; ++k) pk.s[k] = tile[w][u0 + k];
            *(uint4*)(dst + u0) = pk.q;
        }
    }
}

// ---------------- K5 (MFMA): out_d[n,w] = sum_v attr[n,v] * (o_d[n,:] @ Wa[:,v,:])
// block tile 128n x 128w, 4 waves (2x2), per-v K=128 bf16 MFMA, attr applied on f32 acc.
__global__ __launch_bounds__(256) void attrm_kernel(const float* __restrict__ o,
                                                    const float* __restrict__ attr,
                                                    const unsigned short* __restrict__ WaT,
                                                    float* __restrict__ tmp) {
    __shared__ unsigned short sA[128][128];
    __shared__ unsigned short sB[128][128];
    __shared__ float sat[128][AA];
    const int tid = threadIdx.x;
    const int d = blockIdx.y;
    const int nb = blockIdx.x * 128;
    const unsigned short* Wp = WaT + (d == 0 ? 0 : 163840);

    // stage A: o rows (nb..nb+127, dim d) -> bf16, XOR-swizzled (u ^= (n&7)<<3)
    {
        const int n = tid >> 1, half = tid & 1;
        const float4* src = (const float4*)(o + ((size_t)(nb + n) * 4 + d) * 128 + half * 64);
        #pragma unroll
        for (int j = 0; j < 16; ++j) {
            const float4 val = src[j];
            const int u0 = (half * 64 + j * 4) ^ ((n & 7) << 3);
            u16x4 pk;
            pk.x = f2bf(val.x); pk.y = f2bf(val.y); pk.z = f2bf(val.z); pk.w = f2bf(val.w);
            *(u16x4*)&sA[n][u0] = pk;
        }
    }
    for (int i = tid; i < 128 * AA; i += 256) ((float*)sat)[i] = attr[(size_t)nb * AA + i];

    const int wid = tid >> 6, lane = tid & 63;
    const int wr = wid >> 1, wc = wid & 1;
    const int lrow = lane & 15, lk = lane >> 4;

    f32x4 tot[4][4];
    #pragma unroll
    for (int mf = 0; mf < 4; ++mf)
        #pragma unroll
        for (int cf = 0; cf < 4; ++cf) tot[mf][cf] = (f32x4){0.f, 0.f, 0.f, 0.f};

    for (int v = 0; v < AA; ++v) {
        __syncthreads();
        {
            const uint4* src = (const uint4*)(Wp + (size_t)v * 16384);
            #pragma unroll
            for (int j = 0; j < 8; ++j) {
                const int cidx = tid + j * 256;
                const int w = cidx >> 4;
                const int u0 = ((cidx & 15) * 8) ^ ((w & 7) << 3);
                const uint4 val = src[cidx];
                *(uint4*)&sB[w][u0] = val;
            }
        }
        __syncthreads();

        f32x4 acc[4][4];
        #pragma unroll
        for (int mf = 0; mf < 4; ++mf)
            #pragma unroll
            for (int cf = 0; cf < 4; ++cf) acc[mf][cf] = (f32x4){0.f, 0.f, 0.f, 0.f};

        #pragma unroll
        for (int ks = 0; ks < 4; ++ks) {
            const int ku = ks * 32 + lk * 8;
            short8_t a[4], b[4];
            #pragma unroll
            for (int mf = 0; mf < 4; ++mf) {
                const int row = wr * 64 + mf * 16 + lrow;
                a[mf] = *(const short8_t*)&sA[row][ku ^ ((row & 7) << 3)];
            }
            #pragma unroll
            for (int cf = 0; cf < 4; ++cf) {
                const int col = wc * 64 + cf * 16 + lrow;
                b[cf] = *(const short8_t*)&sB[col][ku ^ ((col & 7) << 3)];
            }
            #pragma unroll
            for (int mf = 0; mf < 4; ++mf)
                #pragma unroll
                for (int cf = 0; cf < 4; ++cf)
                    acc[mf][cf] = __builtin_amdgcn_mfma_f32_16x16x32_bf16(a[mf], b[cf], acc[mf][cf], 0, 0, 0);
        }

        // weight by attr[n, v] on f32 accumulator
        #pragma unroll
        for (int mf = 0; mf < 4; ++mf) {
            const int row0 = wr * 64 + mf * 16 + lk * 4;
            #pragma unroll
            for (int j = 0; j < 4; ++j) {
                const float wj = sat[row0 + j][v];
                #pragma unroll
                for (int cf = 0; cf < 4; ++cf)
                    tot[mf][cf][j] += wj * acc[mf][cf][j];
            }
        }
    }

    const float inv_ca = 0.027950849718747373f;
    #pragma unroll
    for (int mf = 0; mf < 4; ++mf) {
        #pragma unroll
        for (int j = 0; j < 4; ++j) {
            const int n = nb + wr * 64 + mf * 16 + lk * 4 + j;
            #pragma unroll
            for (int cf = 0; cf < 4; ++cf) {
                const int col = wc * 64 + cf * 16 + lrow;
                tmp[(size_t)d * 2048000 + (size_t)n * 128 + col] = tot[mf][cf][j] * inv_ca;
            }
        }
    }
}

// ---------------- pack: out[n][w][0..3] = {tmp_d planes} as float4
__global__ __launch_bounds__(256) void pack_kernel(const float* __restrict__ tmp,
                                                   float4* __restrict__ out4) {
    const size_t e = (size_t)blockIdx.x * 256 + threadIdx.x;
    out4[e] = make_float4(tmp[e], tmp[2048000 + e], tmp[4096000 + e], tmp[6144000 + e]);
}

extern "C" void kernel_launch(void* const* d_in, const int* in_sizes, int n_in,
                              void* d_out, int out_size, void* d_ws, size_t ws_size,
                              hipStream_t stream) {
    const float* nf    = (const float*)d_in[0];
    const float* attr  = (const float*)d_in[1];
    const float* sph   = (const float*)d_in[2];
    const float* rb    = (const float*)d_in[3];
    const int*   ei    = (const int*)d_in[4];
    const float* Wpre0 = (const float*)d_in[5];
    const float* Wpre1 = (const float*)d_in[6];
    const float* Wm1   = (const float*)d_in[7];
    const float* Wm2   = (const float*)d_in[8];
    const float* Wm3   = (const float*)d_in[9];
    const float* Wpost0= (const float*)d_in[10];
    const float* Wpost1= (const float*)d_in[11];
    const float* Wa0   = (const float*)d_in[12];
    const float* Wa1   = (const float*)d_in[13];
    float* out = (float*)d_out;

    float* ws = (float*)d_ws;
    // layout (float units):
    // h4 / o : [0, 8192000)           -- h4 dead after wmsg; o written by posto
    // hmS    : [8192000, 16384000)    (E,64) bf16
    // Acat   : [16384000, 32768000)   (N,1024) f32 -- dead after posto
    //   tmp  = Acat[0 .. 8192000)     4 planes (N,128) f32   (attrm output)
    //   WaT  = Acat[8192000 ..)       2*10*128*128 bf16      (watT output)
    // ints + Ys after Acat region
    float4* h4 = (float4*)ws;
    unsigned short* hmS = (unsigned short*)(ws + (size_t)8192000);
    float* Acat = ws + (size_t)16384000;
    int* perm = (int*)(Acat + (size_t)16384000);  // 256000
    int* cur  = perm + 256000;                     // 16384
    int* cnt  = cur + 16384;                       // 16384
    int* ss   = cnt + 16384;                       // 256000
    int* rs   = ss + 256000;                       // 256000
    float4* Ys = (float4*)(rs + 256000);           // 256000 float4
    float* o = ws;                                  // (N,4,128), aliases h4
    float* tmp = Acat;                              // 4 x 2,048,000 f32
    unsigned short* WaT = (unsigned short*)(Acat + (size_t)8192000);

    hipMemsetAsync(Acat, 0, (size_t)NN * 1024 * sizeof(float), stream);
    hipMemsetAsync(cnt, 0, 16384 * sizeof(int), stream);

    pre_kernel<<<500, 256, 0, stream>>>(nf, Wpre0, Wpre1, h4);
    count_kernel<<<EE / 256, 256, 0, stream>>>(ei, cnt);
    scan_kernel<<<1, 1024, 0, stream>>>(cnt, cur);
    fill_kernel<<<EE / 256, 256, 0, stream>>>(ei, cur, perm);
    gather_kernel<<<EE / 256, 256, 0, stream>>>(perm, ei, (const float4*)sph, ss, rs, Ys);
    mlp_kernel<<<EE / 256, 256, 0, stream>>>(rb, Wm1, Wm2, perm, hmS);
    wmsg_kernel<<<EE / 32, 256, 0, stream>>>(hmS, Wm3, ss, rs, Ys, h4, Acat);
    posto_kernel<<<NN / 16, 256, 0, stream>>>(Acat, Wpost0, Wpost1, o);
    watT_kernel<<<dim3(AA, 2), 256, 0, stream>>>(Wa0, Wa1, WaT);
    attrm_kernel<<<dim3(NN / 128, 4), 256, 0, stream>>>(o, attr, WaT, tmp);
    pack_kernel<<<8000, 256, 0, stream>>>(tmp, (float4*)out);
}